// Round 6
// baseline (112.267 us; speedup 1.0000x reference)
//
#include <hip/hip_runtime.h>
#include <hip/hip_fp16.h>
#include <hip/hip_cooperative_groups.h>
namespace cg = cooperative_groups;

#define H 1024
#define W 2048
#define HW (H * W)
#define LOG19 2.9444389791664403f
#define TY 8        // rows per strip
#define NT 576      // 9 waves
#define NVERT 528   // vertical threads: 528 x 2 = 1056 padded cols
#define BCOLS 1024  // output cols per block (half width)
#define NG 132      // 8-col groups over 1056 padded cols
#define GRP 41      // lcnt words/group (41 mod 32 = 9, coprime)
#define LGS 9       // lent words/group
#define GSS 11      // gsum words/group: 10 u16x2 + 1 float

typedef __attribute__((ext_vector_type(4))) float f32x4;
typedef __attribute__((ext_vector_type(2))) float f32x2;
typedef __attribute__((ext_vector_type(2))) unsigned int u32x2;

static __device__ __forceinline__ unsigned int f2h_bits(float f) {
    __half h = __float2half_rn(f);
    unsigned short b;
    __builtin_memcpy(&b, &h, 2);
    return (unsigned int)b;
}
static __device__ __forceinline__ float h2f_bits(unsigned int b) {
    unsigned short s = (unsigned short)b;
    __half h;
    __builtin_memcpy(&h, &s, 2);
    return __half2float(h);
}

// Vertical SWAR accumulate from packed (fp16 entropy | class<<24)
#define VACC(yy, SGN)                                                                 \
    if (vvalid) {                                                                     \
        u32x2 pw = *reinterpret_cast<const u32x2*>(packed + (size_t)(yy)*W + gcol0);  \
        _Pragma("unroll") for (int j = 0; j < 2; j++) {                               \
            unsigned int wv = pw[j];                                                  \
            unsigned int cc = wv >> 24;                                               \
            unsigned int wi = cc >> 2, bit = 1u << ((cc & 3u) * 8u);                  \
            _Pragma("unroll") for (int k = 0; k < 5; k++)                             \
                vc[j * 5 + k] SGN## = (wi == (unsigned)k) ? bit : 0u;                 \
            ve[j] SGN## = h2f_bits(wv);                                               \
        }                                                                             \
    }
#define VSLIDE(y)                         \
    {                                     \
        int ya = (y) + 17, yr = (y) - 16; \
        if (ya < H) VACC(ya, +)           \
        if (yr >= 0) VACC(yr, -)          \
    }
#define PUBLISH(b)                                                              \
    if (tid < NVERT) {                                                          \
        unsigned int ps[10];                                                    \
        float pe = ve[0] + ve[1];                                               \
        _Pragma("unroll") for (int k = 0; k < 5; k++) {                         \
            ps[2 * k] = (vc[k] & 0x00FF00FFu) + (vc[5 + k] & 0x00FF00FFu);      \
            ps[2 * k + 1] = ((vc[k] >> 8) & 0x00FF00FFu) +                      \
                            ((vc[5 + k] >> 8) & 0x00FF00FFu);                   \
        }                                                                       \
        int g = tid >> 2, sl0 = (2 * tid) & 7;                                  \
        _Pragma("unroll") for (int k = 0; k < 5; k++) {                         \
            lcnt[b][g * GRP + sl0 * 5 + k] = vc[k];                             \
            lcnt[b][g * GRP + (sl0 + 1) * 5 + k] = vc[5 + k];                   \
        }                                                                       \
        lent[b][g * LGS + sl0] = ve[0];                                         \
        lent[b][g * LGS + sl0 + 1] = ve[1];                                     \
        _Pragma("unroll") for (int q = 0; q < 10; q++) {                        \
            ps[q] += __shfl_xor(ps[q], 1);                                      \
            ps[q] += __shfl_xor(ps[q], 2);                                      \
        }                                                                       \
        pe += __shfl_xor(pe, 1);                                                \
        pe += __shfl_xor(pe, 2);                                                \
        if ((tid & 3) == 0) {                                                   \
            _Pragma("unroll") for (int q = 0; q < 10; q++)                      \
                gsum[b][g * GSS + q] = ps[q];                                   \
            gsum[b][g * GSS + 10] = __float_as_uint(pe);                        \
        }                                                                       \
    }

__global__ __launch_bounds__(NT, 3) void fused_frs(
    const float* __restrict__ logit,
    unsigned int* __restrict__ packed,
    float* __restrict__ out_score,
    float* __restrict__ out_imp,
    float* __restrict__ out_unc) {
    __shared__ float lut[1090];                 // n*ln(n)
    __shared__ unsigned int lcnt[2][NG * GRP];  // per-col u8x4 counts
    __shared__ float lent[2][NG * LGS];         // per-col entropy sums
    __shared__ unsigned int gsum[2][NG * GSS];  // 8-col group sums
    int tid = threadIdx.x;
    int bid = blockIdx.x;
    // XCD-chunked: 16 adjacent strips (x2 halves) per XCD; phase 1 writes the
    // same rows phase 2 reads, per XCD.
    int xcd = bid & 7, idx = bid >> 3;
    int strip = xcd * 16 + (idx >> 1);
    int colbase = (idx & 1) * BCOLS;
    int y0 = strip * TY;

    // ================= Phase 1: softmax entropy + argmax =================
    if (tid >= 512) {
        for (int n = tid - 512; n < 1090; n += 64)
            lut[n] = n ? (float)n * __logf((float)n) : 0.f;
    } else {
        for (int it = 0; it < 8; ++it) {
            int pp = (it << 9) | tid;
            int row = y0 + (pp >> 9);
            int col = colbase + ((pp & 511) << 1);
            size_t p0 = (size_t)row * W + col;
            f32x2 v[19];
#pragma unroll
            for (int c = 0; c < 19; c++)
                v[c] = __builtin_nontemporal_load(
                    reinterpret_cast<const f32x2*>(logit + (size_t)c * HW + p0));
            f32x2 m = v[0];
            int am0 = 0, am1 = 0;
#pragma unroll
            for (int c = 1; c < 19; c++) {
                if (v[c][0] > m[0]) { m[0] = v[c][0]; am0 = c; }
                if (v[c][1] > m[1]) { m[1] = v[c][1]; am1 = c; }
            }
            f32x2 S = {0.f, 0.f}, T = {0.f, 0.f};
#pragma unroll
            for (int c = 0; c < 19; c++) {
#pragma unroll
                for (int j = 0; j < 2; j++) {
                    float d = v[c][j] - m[j];
                    float e = __expf(d);
                    S[j] += e;
                    T[j] += d * e;
                }
            }
            u32x2 wout;
            wout[0] = f2h_bits((__logf(S[0]) - T[0] / S[0]) * (1.f / LOG19)) |
                      ((unsigned)am0 << 24);
            wout[1] = f2h_bits((__logf(S[1]) - T[1] / S[1]) * (1.f / LOG19)) |
                      ((unsigned)am1 << 24);
            *reinterpret_cast<u32x2*>(packed + p0) = wout;  // keep in cache
        }
    }
    cg::this_grid().sync();

    // ================= Phase 2: fused 33x33 box + score =================
    int gcol0 = colbase - 16 + 2 * tid;  // 2 padded cols/thread
    bool vvalid = (tid < NVERT) && ((unsigned)gcol0 < (unsigned)W);
    unsigned int vc[10];
#pragma unroll
    for (int i = 0; i < 10; i++) vc[i] = 0u;
    float ve[2] = {0.f, 0.f};
    {
        int ylo = max(y0 - 16, 0), yhi = min(y0 + 16, H - 1);
        for (int yy = ylo; yy <= yhi; yy++) VACC(yy, +)
    }

#pragma unroll
    for (int p = 0; p < TY / 2; p++) {
        int yA = y0 + 2 * p;
        PUBLISH(0)
        VSLIDE(yA)  // -> row yA+1
        PUBLISH(1)
        __syncthreads();

        // prefetch next pair's vertical slide FIRST (loads in flight while
        // the horizontal phase computes)
        if (p < TY / 2 - 1) VSLIDE(yA + 1)

        if (tid < 256) {
            int rsel = tid >> 7;  // which buffered row
            int hq = tid & 127;
            int x0h = hq * 8;  // block-local out col
            int y = yA + rsel;
            unsigned int ha[10];
            float hes;
            {  // warm-up: groups hq..hq+3 + element at padded idx x0h+32
#pragma unroll
                for (int q = 0; q < 10; q++)
                    ha[q] = gsum[rsel][hq * GSS + q] + gsum[rsel][(hq + 1) * GSS + q] +
                            gsum[rsel][(hq + 2) * GSS + q] + gsum[rsel][(hq + 3) * GSS + q];
                hes = __uint_as_float(gsum[rsel][hq * GSS + 10]) +
                      __uint_as_float(gsum[rsel][(hq + 1) * GSS + 10]) +
                      __uint_as_float(gsum[rsel][(hq + 2) * GSS + 10]) +
                      __uint_as_float(gsum[rsel][(hq + 3) * GSS + 10]);
#pragma unroll
                for (int k = 0; k < 5; k++) {
                    unsigned int wv = lcnt[rsel][(hq + 4) * GRP + k];
                    ha[2 * k] += wv & 0x00FF00FFu;
                    ha[2 * k + 1] += (wv >> 8) & 0x00FF00FFu;
                }
                hes += lent[rsel][(hq + 4) * LGS];
            }
            int rcount = min(y + 16, H - 1) - max(y - 16, 0) + 1;
            f32x4 osc[2], oim[2], oun[2];
#pragma unroll
            for (int s = 0; s < 8; s++) {
                int gx = colbase + x0h + s;
                int ccount = min(gx + 16, W - 1) - max(gx - 16, 0) + 1;
                int Tw = rcount * ccount;
                float invT = 1.0f / (float)Tw;
                float sum = 0.f;
#pragma unroll
                for (int k = 0; k < 5; k++) {
                    unsigned int a = ha[2 * k], b = ha[2 * k + 1];
                    sum += lut[a & 0xFFFFu] + lut[b & 0xFFFFu] + lut[a >> 16];
                    if (k < 4) sum += lut[b >> 16];
                }
                float imp = (lut[Tw] - sum) * invT * (1.0f / LOG19);
                float unc = hes * invT;
                osc[s >> 2][s & 3] = imp * unc;
                oim[s >> 2][s & 3] = imp;
                oun[s >> 2][s & 3] = unc;
                if (s < 7) {  // slide padded window [x0h+s, x0h+s+32] -> +1
                    int ga = hq + ((s + 33) >> 3), ja = (s + 33) & 7;
                    hes += lent[rsel][ga * LGS + ja] - lent[rsel][hq * LGS + s];
#pragma unroll
                    for (int k = 0; k < 5; k++) {
                        unsigned int wa = lcnt[rsel][ga * GRP + ja * 5 + k];
                        unsigned int wr = lcnt[rsel][hq * GRP + s * 5 + k];
                        ha[2 * k] += (wa & 0x00FF00FFu) - (wr & 0x00FF00FFu);
                        ha[2 * k + 1] += ((wa >> 8) & 0x00FF00FFu) - ((wr >> 8) & 0x00FF00FFu);
                    }
                }
            }
            size_t qo = (size_t)y * W + colbase + x0h;
            __builtin_nontemporal_store(osc[0], reinterpret_cast<f32x4*>(out_score + qo));
            __builtin_nontemporal_store(osc[1], reinterpret_cast<f32x4*>(out_score + qo + 4));
            __builtin_nontemporal_store(oim[0], reinterpret_cast<f32x4*>(out_imp + qo));
            __builtin_nontemporal_store(oim[1], reinterpret_cast<f32x4*>(out_imp + qo + 4));
            __builtin_nontemporal_store(oun[0], reinterpret_cast<f32x4*>(out_unc + qo));
            __builtin_nontemporal_store(oun[1], reinterpret_cast<f32x4*>(out_unc + qo + 4));
        }
        __syncthreads();  // reads done before next pair's publish
    }
}

extern "C" void kernel_launch(void* const* d_in, const int* in_sizes, int n_in,
                              void* d_out, int out_size, void* d_ws, size_t ws_size,
                              hipStream_t stream) {
    const float* logit = (const float*)d_in[0];
    float* out = (float*)d_out;
    unsigned int* packed = (unsigned int*)d_ws;  // 8 MB
    float* o_score = out;
    float* o_imp = out + HW;
    float* o_unc = out + 2 * HW;

    void* args[] = {(void*)&logit, (void*)&packed, (void*)&o_score, (void*)&o_imp,
                    (void*)&o_unc};
    hipLaunchCooperativeKernel((void*)fused_frs, dim3(256), dim3(NT), args, 0, stream);
}

// Round 7
// 65.789 us; speedup vs baseline: 1.7065x; 1.7065x over previous
//
#include <hip/hip_runtime.h>
#include <hip/hip_fp16.h>

#define H 1024
#define W 2048
#define HW (H * W)
#define LOG19 2.9444389791664403f
#define TY 4          // rows per block
#define NT 1024       // threads per block (16 waves)
#define GRP 41        // lcnt words per 8-col group (41 mod 32 = 9, coprime)
#define NGRP 260      // padded cols 2080 / 8
#define LGS 9         // lent words per group (coprime with 32)
#define GSS 11        // gsum words per group: 10 u16x2 + 1 float

typedef __attribute__((ext_vector_type(4))) float f32x4;
typedef __attribute__((ext_vector_type(2))) unsigned int u32x2;
typedef __attribute__((ext_vector_type(4))) unsigned int u32x4;

static __device__ __forceinline__ unsigned int f2h_bits(float f) {
    __half h = __float2half_rn(f);
    unsigned short b;
    __builtin_memcpy(&b, &h, 2);
    return (unsigned int)b;
}
static __device__ __forceinline__ float h2f_bits(unsigned int b) {
    unsigned short s = (unsigned short)b;
    __half h;
    __builtin_memcpy(&h, &s, 2);
    return __half2float(h);
}

// ---------------- K1: softmax entropy + argmax -> packed u32/px ----------------
__global__ __launch_bounds__(256) void k1_entropy_argmax(
    const float* __restrict__ logit,
    unsigned int* __restrict__ packed) {
    int q = blockIdx.x * 256 + threadIdx.x;
    int p0 = q * 4;
    f32x4 v[19];
#pragma unroll
    for (int c = 0; c < 19; c++)
        v[c] = *reinterpret_cast<const f32x4*>(logit + (size_t)c * HW + p0);
    f32x4 m = v[0];
    int am[4] = {0, 0, 0, 0};
#pragma unroll
    for (int c = 1; c < 19; c++) {
#pragma unroll
        for (int j = 0; j < 4; j++)
            if (v[c][j] > m[j]) { m[j] = v[c][j]; am[j] = c; }
    }
    f32x4 S = (f32x4)(0.f), T = (f32x4)(0.f);
#pragma unroll
    for (int c = 0; c < 19; c++) {
#pragma unroll
        for (int j = 0; j < 4; j++) {
            float d = v[c][j] - m[j];
            float e = __expf(d);
            S[j] += e;
            T[j] += d * e;
        }
    }
    u32x4 w;
#pragma unroll
    for (int j = 0; j < 4; j++) {
        float ent = (__logf(S[j]) - T[j] / S[j]) * (1.0f / LOG19);
        w[j] = f2h_bits(ent) | ((unsigned int)am[j] << 24);
    }
    *reinterpret_cast<u32x4*>(packed + p0) = w;
}

// ---------------- K23: fused box + score (R4 geometry, packed input) ----------------
// 1024 threads, TY=4 rows/block, grid=256 (XCD-chunked strips).
// Vertical: 2 cols/thread, u8x4-SWAR 33-tap sliding sums in registers.
// Publish: elements + shfl-reduced 8-col group sums per row, 2-row dbuf.
// Horizontal: tid<512, two half-blocks x 256 threads x 8 px; warm-up from
// 4 group sums + 1 element; per-px slide + n*ln(n) LUT epilogue.
#define VACC(yy, SGN)                                                                \
    {                                                                                \
        u32x2 pw = *reinterpret_cast<const u32x2*>(packed + (size_t)(yy)*W + x0);    \
        _Pragma("unroll") for (int j = 0; j < 2; j++) {                              \
            unsigned int wv = pw[j];                                                 \
            unsigned int cc = wv >> 24;                                              \
            unsigned int wi = cc >> 2, bit = 1u << ((cc & 3u) * 8u);                 \
            _Pragma("unroll") for (int k = 0; k < 5; k++)                            \
                vc[j * 5 + k] SGN## = (wi == (unsigned)k) ? bit : 0u;                \
            ve[j] SGN## = h2f_bits(wv);                                              \
        }                                                                            \
    }
#define VSLIDE(y)                         \
    {                                     \
        int ya = (y) + 17, yr = (y) - 16; \
        if (ya < H) VACC(ya, +)           \
        if (yr >= 0) VACC(yr, -)          \
    }
#define PUBLISH(b)                                                              \
    {                                                                           \
        unsigned int ps[10];                                                    \
        float pe = ve[0] + ve[1];                                               \
        _Pragma("unroll") for (int k = 0; k < 5; k++) {                         \
            ps[2 * k] = (vc[k] & 0x00FF00FFu) + (vc[5 + k] & 0x00FF00FFu);      \
            ps[2 * k + 1] = ((vc[k] >> 8) & 0x00FF00FFu) +                      \
                            ((vc[5 + k] >> 8) & 0x00FF00FFu);                   \
        }                                                                       \
        _Pragma("unroll") for (int j = 0; j < 2; j++) {                         \
            int i = x0 + 16 + j;                                                \
            int g = i >> 3, sl = i & 7;                                         \
            _Pragma("unroll") for (int k = 0; k < 5; k++)                       \
                lcnt[b][g * GRP + sl * 5 + k] = vc[j * 5 + k];                  \
            lent[b][g * LGS + sl] = ve[j];                                      \
        }                                                                       \
        _Pragma("unroll") for (int q = 0; q < 10; q++) {                        \
            ps[q] += __shfl_xor(ps[q], 1);                                      \
            ps[q] += __shfl_xor(ps[q], 2);                                      \
        }                                                                       \
        pe += __shfl_xor(pe, 1);                                                \
        pe += __shfl_xor(pe, 2);                                                \
        if ((tid & 3) == 0) {                                                   \
            int g = (tid >> 2) + 2;                                             \
            _Pragma("unroll") for (int q = 0; q < 10; q++)                      \
                gsum[b][g * GSS + q] = ps[q];                                   \
            gsum[b][g * GSS + 10] = __float_as_uint(pe);                        \
        }                                                                       \
    }

__global__ __launch_bounds__(NT) void k23_box_score(
    const unsigned int* __restrict__ packed,
    float* __restrict__ out_score,
    float* __restrict__ out_imp,
    float* __restrict__ out_unc) {
    __shared__ float lut[1090];                   // n*ln(n)
    __shared__ unsigned int lcnt[2][NGRP * GRP];  // per-col u8x4 counts
    __shared__ float lent[2][NGRP * LGS];         // per-col entropy sums
    __shared__ unsigned int gsum[2][NGRP * GSS];  // 8-col group sums
    int tid = threadIdx.x;
    int strip = ((blockIdx.x & 7) << 5) + (blockIdx.x >> 3);  // XCD-chunked
    int y0 = strip * TY;

    for (int n = tid; n < 1090; n += NT)
        lut[n] = n ? (float)n * __logf((float)n) : 0.f;
    if (tid < 64) {  // element pads: 16 cols each side, both buffers
        int b = tid >> 5, t = tid & 31;
        int i = (t < 16) ? t : (2048 + t);
        int g = i >> 3, sl = i & 7;
#pragma unroll
        for (int k = 0; k < 5; k++) lcnt[b][g * GRP + sl * 5 + k] = 0u;
        lent[b][g * LGS + sl] = 0.f;
    }
    if (tid >= 64 && tid < 64 + 88) {  // group pads {0,1,258,259} x 2 buf x 11
        int idx = tid - 64;
        int b = idx / 44, r = idx % 44;
        int gi = r / 11, q = r % 11;
        int g = (gi < 2) ? gi : (256 + gi);
        gsum[b][g * GSS + q] = 0u;
    }

    int x0 = tid * 2;  // 2 real cols per thread
    unsigned int vc[10];
#pragma unroll
    for (int i = 0; i < 10; i++) vc[i] = 0u;
    float ve[2] = {0.f, 0.f};
    {
        int ylo = max(y0 - 16, 0), yhi = min(y0 + 16, H - 1);
        for (int yy = ylo; yy <= yhi; yy++) VACC(yy, +)
    }

#pragma unroll
    for (int p = 0; p < TY / 2; p++) {
        int yA = y0 + 2 * p;
        PUBLISH(0)
        VSLIDE(yA)  // -> row yA+1
        PUBLISH(1)
        if (p < TY / 2 - 1) VSLIDE(yA + 1)
        __syncthreads();

        if (tid < 512) {
            int half = tid >> 8;
            int hq = tid & 255;
            int x0h = hq * 8;
            int y = yA + half;
            unsigned int ha[10];
            float hes;
            {  // warm-up: groups hq..hq+3 + element at padded col 8*hq+32
#pragma unroll
                for (int q = 0; q < 10; q++)
                    ha[q] = gsum[half][hq * GSS + q] + gsum[half][(hq + 1) * GSS + q] +
                            gsum[half][(hq + 2) * GSS + q] + gsum[half][(hq + 3) * GSS + q];
                hes = __uint_as_float(gsum[half][hq * GSS + 10]) +
                      __uint_as_float(gsum[half][(hq + 1) * GSS + 10]) +
                      __uint_as_float(gsum[half][(hq + 2) * GSS + 10]) +
                      __uint_as_float(gsum[half][(hq + 3) * GSS + 10]);
#pragma unroll
                for (int k = 0; k < 5; k++) {
                    unsigned int wv = lcnt[half][(hq + 4) * GRP + k];
                    ha[2 * k] += wv & 0x00FF00FFu;
                    ha[2 * k + 1] += (wv >> 8) & 0x00FF00FFu;
                }
                hes += lent[half][(hq + 4) * LGS];
            }
            int rcount = min(y + 16, H - 1) - max(y - 16, 0) + 1;
            f32x4 osc[2], oim[2], oun[2];
#pragma unroll
            for (int s = 0; s < 8; s++) {
                int x = x0h + s;
                int ccount = min(x + 16, W - 1) - max(x - 16, 0) + 1;
                int Tw = rcount * ccount;
                float invT = 1.0f / (float)Tw;
                float sum = 0.f;
#pragma unroll
                for (int k = 0; k < 5; k++) {
                    unsigned int a = ha[2 * k], b = ha[2 * k + 1];
                    sum += lut[a & 0xFFFFu] + lut[b & 0xFFFFu] + lut[a >> 16];
                    if (k < 4) sum += lut[b >> 16];
                }
                float imp = (lut[Tw] - sum) * invT * (1.0f / LOG19);
                float unc = hes * invT;
                osc[s >> 2][s & 3] = imp * unc;
                oim[s >> 2][s & 3] = imp;
                oun[s >> 2][s & 3] = unc;
                if (s < 7) {  // slide padded window [x, x+32] -> [x+1, x+33]
                    int ga = hq + ((s + 33) >> 3), ja = (s + 33) & 7;
                    hes += lent[half][ga * LGS + ja] - lent[half][hq * LGS + s];
#pragma unroll
                    for (int k = 0; k < 5; k++) {
                        unsigned int wa = lcnt[half][ga * GRP + ja * 5 + k];
                        unsigned int wr = lcnt[half][hq * GRP + s * 5 + k];
                        ha[2 * k] += (wa & 0x00FF00FFu) - (wr & 0x00FF00FFu);
                        ha[2 * k + 1] += ((wa >> 8) & 0x00FF00FFu) - ((wr >> 8) & 0x00FF00FFu);
                    }
                }
            }
            size_t qo = (size_t)y * W + x0h;
            __builtin_nontemporal_store(osc[0], reinterpret_cast<f32x4*>(out_score + qo));
            __builtin_nontemporal_store(osc[1], reinterpret_cast<f32x4*>(out_score + qo + 4));
            __builtin_nontemporal_store(oim[0], reinterpret_cast<f32x4*>(out_imp + qo));
            __builtin_nontemporal_store(oim[1], reinterpret_cast<f32x4*>(out_imp + qo + 4));
            __builtin_nontemporal_store(oun[0], reinterpret_cast<f32x4*>(out_unc + qo));
            __builtin_nontemporal_store(oun[1], reinterpret_cast<f32x4*>(out_unc + qo + 4));
        }
        __syncthreads();  // reads done before next pair's publish
    }
}

extern "C" void kernel_launch(void* const* d_in, const int* in_sizes, int n_in,
                              void* d_out, int out_size, void* d_ws, size_t ws_size,
                              hipStream_t stream) {
    const float* logit = (const float*)d_in[0];
    float* out = (float*)d_out;
    unsigned int* packed = (unsigned int*)d_ws;  // 8 MB

    k1_entropy_argmax<<<HW / 1024, 256, 0, stream>>>(logit, packed);
    k23_box_score<<<256, NT, 0, stream>>>(packed, out, out + HW, out + 2 * HW);
}

// Round 8
// 63.681 us; speedup vs baseline: 1.7630x; 1.0331x over previous
//
#include <hip/hip_runtime.h>
#include <hip/hip_fp16.h>

#define H 1024
#define W 2048
#define HW (H * W)
#define LOG19 2.9444389791664403f
#define TY 4          // rows per block
#define NT 1024       // threads per block (16 waves)
#define GRP 41        // lcnt words per 8-col group (41 mod 32 = 9, coprime)
#define NGRP 260      // padded cols 2080 / 8
#define LGS 9         // lent words per group (coprime with 32)
#define GSS 11        // gsum words per group: 10 u16x2 + 1 float

typedef __attribute__((ext_vector_type(4))) float f32x4;
typedef __attribute__((ext_vector_type(2))) float f32x2;
typedef __attribute__((ext_vector_type(2))) unsigned int u32x2;

static __device__ __forceinline__ unsigned int f2h_bits(float f) {
    __half h = __float2half_rn(f);
    unsigned short b;
    __builtin_memcpy(&b, &h, 2);
    return (unsigned int)b;
}
static __device__ __forceinline__ float h2f_bits(unsigned int b) {
    unsigned short s = (unsigned short)b;
    __half h;
    __builtin_memcpy(&h, &s, 2);
    return __half2float(h);
}

// ---------------- K1: softmax entropy + argmax -> packed u32/px ----------------
// 2 px/thread, f32x2 loads (38 VGPR for v[19]) -> 8 waves/SIMD occupancy.
// No max-subtraction in the exp loop: H = ln S - (sum x*e^x)/S, safe for
// |x| <~ 60; argmax still tracks the running max.
__global__ __launch_bounds__(256, 8) void k1_entropy_argmax(
    const float* __restrict__ logit,
    unsigned int* __restrict__ packed) {
    int q = blockIdx.x * 256 + threadIdx.x;
    int p0 = q * 2;
    f32x2 v[19];
#pragma unroll
    for (int c = 0; c < 19; c++)
        v[c] = *reinterpret_cast<const f32x2*>(logit + (size_t)c * HW + p0);
    f32x2 m = v[0];
    int am0 = 0, am1 = 0;
#pragma unroll
    for (int c = 1; c < 19; c++) {
        if (v[c][0] > m[0]) { m[0] = v[c][0]; am0 = c; }
        if (v[c][1] > m[1]) { m[1] = v[c][1]; am1 = c; }
    }
    f32x2 S = {0.f, 0.f}, T = {0.f, 0.f};
#pragma unroll
    for (int c = 0; c < 19; c++) {
#pragma unroll
        for (int j = 0; j < 2; j++) {
            float e = __expf(v[c][j]);
            S[j] += e;
            T[j] = __builtin_fmaf(v[c][j], e, T[j]);
        }
    }
    u32x2 w;
    w[0] = f2h_bits((__logf(S[0]) - T[0] / S[0]) * (1.0f / LOG19)) | ((unsigned)am0 << 24);
    w[1] = f2h_bits((__logf(S[1]) - T[1] / S[1]) * (1.0f / LOG19)) | ((unsigned)am1 << 24);
    *reinterpret_cast<u32x2*>(packed + p0) = w;
}

// ---------------- K23: fused box + score (unchanged from R7) ----------------
// 1024 threads, TY=4 rows/block, grid=256 (XCD-chunked strips).
// Vertical: 2 cols/thread, u8x4-SWAR 33-tap sliding sums in registers.
// Publish: elements + shfl-reduced 8-col group sums per row, 2-row dbuf.
// Horizontal: tid<512, two half-blocks x 256 threads x 8 px; warm-up from
// 4 group sums + 1 element; per-px slide + n*ln(n) LUT epilogue.
#define VACC(yy, SGN)                                                                \
    {                                                                                \
        u32x2 pw = *reinterpret_cast<const u32x2*>(packed + (size_t)(yy)*W + x0);    \
        _Pragma("unroll") for (int j = 0; j < 2; j++) {                              \
            unsigned int wv = pw[j];                                                 \
            unsigned int cc = wv >> 24;                                              \
            unsigned int wi = cc >> 2, bit = 1u << ((cc & 3u) * 8u);                 \
            _Pragma("unroll") for (int k = 0; k < 5; k++)                            \
                vc[j * 5 + k] SGN## = (wi == (unsigned)k) ? bit : 0u;                \
            ve[j] SGN## = h2f_bits(wv);                                              \
        }                                                                            \
    }
#define VSLIDE(y)                         \
    {                                     \
        int ya = (y) + 17, yr = (y) - 16; \
        if (ya < H) VACC(ya, +)           \
        if (yr >= 0) VACC(yr, -)          \
    }
#define PUBLISH(b)                                                              \
    {                                                                           \
        unsigned int ps[10];                                                    \
        float pe = ve[0] + ve[1];                                               \
        _Pragma("unroll") for (int k = 0; k < 5; k++) {                         \
            ps[2 * k] = (vc[k] & 0x00FF00FFu) + (vc[5 + k] & 0x00FF00FFu);      \
            ps[2 * k + 1] = ((vc[k] >> 8) & 0x00FF00FFu) +                      \
                            ((vc[5 + k] >> 8) & 0x00FF00FFu);                   \
        }                                                                       \
        _Pragma("unroll") for (int j = 0; j < 2; j++) {                         \
            int i = x0 + 16 + j;                                                \
            int g = i >> 3, sl = i & 7;                                         \
            _Pragma("unroll") for (int k = 0; k < 5; k++)                       \
                lcnt[b][g * GRP + sl * 5 + k] = vc[j * 5 + k];                  \
            lent[b][g * LGS + sl] = ve[j];                                      \
        }                                                                       \
        _Pragma("unroll") for (int q = 0; q < 10; q++) {                        \
            ps[q] += __shfl_xor(ps[q], 1);                                      \
            ps[q] += __shfl_xor(ps[q], 2);                                      \
        }                                                                       \
        pe += __shfl_xor(pe, 1);                                                \
        pe += __shfl_xor(pe, 2);                                                \
        if ((tid & 3) == 0) {                                                   \
            int g = (tid >> 2) + 2;                                             \
            _Pragma("unroll") for (int q = 0; q < 10; q++)                      \
                gsum[b][g * GSS + q] = ps[q];                                   \
            gsum[b][g * GSS + 10] = __float_as_uint(pe);                        \
        }                                                                       \
    }

__global__ __launch_bounds__(NT) void k23_box_score(
    const unsigned int* __restrict__ packed,
    float* __restrict__ out_score,
    float* __restrict__ out_imp,
    float* __restrict__ out_unc) {
    __shared__ float lut[1090];                   // n*ln(n)
    __shared__ unsigned int lcnt[2][NGRP * GRP];  // per-col u8x4 counts
    __shared__ float lent[2][NGRP * LGS];         // per-col entropy sums
    __shared__ unsigned int gsum[2][NGRP * GSS];  // 8-col group sums
    int tid = threadIdx.x;
    int strip = ((blockIdx.x & 7) << 5) + (blockIdx.x >> 3);  // XCD-chunked
    int y0 = strip * TY;

    for (int n = tid; n < 1090; n += NT)
        lut[n] = n ? (float)n * __logf((float)n) : 0.f;
    if (tid < 64) {  // element pads: 16 cols each side, both buffers
        int b = tid >> 5, t = tid & 31;
        int i = (t < 16) ? t : (2048 + t);
        int g = i >> 3, sl = i & 7;
#pragma unroll
        for (int k = 0; k < 5; k++) lcnt[b][g * GRP + sl * 5 + k] = 0u;
        lent[b][g * LGS + sl] = 0.f;
    }
    if (tid >= 64 && tid < 64 + 88) {  // group pads {0,1,258,259} x 2 buf x 11
        int idx = tid - 64;
        int b = idx / 44, r = idx % 44;
        int gi = r / 11, q = r % 11;
        int g = (gi < 2) ? gi : (256 + gi);
        gsum[b][g * GSS + q] = 0u;
    }

    int x0 = tid * 2;  // 2 real cols per thread
    unsigned int vc[10];
#pragma unroll
    for (int i = 0; i < 10; i++) vc[i] = 0u;
    float ve[2] = {0.f, 0.f};
    {
        int ylo = max(y0 - 16, 0), yhi = min(y0 + 16, H - 1);
        for (int yy = ylo; yy <= yhi; yy++) VACC(yy, +)
    }

#pragma unroll
    for (int p = 0; p < TY / 2; p++) {
        int yA = y0 + 2 * p;
        PUBLISH(0)
        VSLIDE(yA)  // -> row yA+1
        PUBLISH(1)
        if (p < TY / 2 - 1) VSLIDE(yA + 1)
        __syncthreads();

        if (tid < 512) {
            int half = tid >> 8;
            int hq = tid & 255;
            int x0h = hq * 8;
            int y = yA + half;
            unsigned int ha[10];
            float hes;
            {  // warm-up: groups hq..hq+3 + element at padded col 8*hq+32
#pragma unroll
                for (int q = 0; q < 10; q++)
                    ha[q] = gsum[half][hq * GSS + q] + gsum[half][(hq + 1) * GSS + q] +
                            gsum[half][(hq + 2) * GSS + q] + gsum[half][(hq + 3) * GSS + q];
                hes = __uint_as_float(gsum[half][hq * GSS + 10]) +
                      __uint_as_float(gsum[half][(hq + 1) * GSS + 10]) +
                      __uint_as_float(gsum[half][(hq + 2) * GSS + 10]) +
                      __uint_as_float(gsum[half][(hq + 3) * GSS + 10]);
#pragma unroll
                for (int k = 0; k < 5; k++) {
                    unsigned int wv = lcnt[half][(hq + 4) * GRP + k];
                    ha[2 * k] += wv & 0x00FF00FFu;
                    ha[2 * k + 1] += (wv >> 8) & 0x00FF00FFu;
                }
                hes += lent[half][(hq + 4) * LGS];
            }
            int rcount = min(y + 16, H - 1) - max(y - 16, 0) + 1;
            f32x4 osc[2], oim[2], oun[2];
#pragma unroll
            for (int s = 0; s < 8; s++) {
                int x = x0h + s;
                int ccount = min(x + 16, W - 1) - max(x - 16, 0) + 1;
                int Tw = rcount * ccount;
                float invT = 1.0f / (float)Tw;
                float sum = 0.f;
#pragma unroll
                for (int k = 0; k < 5; k++) {
                    unsigned int a = ha[2 * k], b = ha[2 * k + 1];
                    sum += lut[a & 0xFFFFu] + lut[b & 0xFFFFu] + lut[a >> 16];
                    if (k < 4) sum += lut[b >> 16];
                }
                float imp = (lut[Tw] - sum) * invT * (1.0f / LOG19);
                float unc = hes * invT;
                osc[s >> 2][s & 3] = imp * unc;
                oim[s >> 2][s & 3] = imp;
                oun[s >> 2][s & 3] = unc;
                if (s < 7) {  // slide padded window [x, x+32] -> [x+1, x+33]
                    int ga = hq + ((s + 33) >> 3), ja = (s + 33) & 7;
                    hes += lent[half][ga * LGS + ja] - lent[half][hq * LGS + s];
#pragma unroll
                    for (int k = 0; k < 5; k++) {
                        unsigned int wa = lcnt[half][ga * GRP + ja * 5 + k];
                        unsigned int wr = lcnt[half][hq * GRP + s * 5 + k];
                        ha[2 * k] += (wa & 0x00FF00FFu) - (wr & 0x00FF00FFu);
                        ha[2 * k + 1] += ((wa >> 8) & 0x00FF00FFu) - ((wr >> 8) & 0x00FF00FFu);
                    }
                }
            }
            size_t qo = (size_t)y * W + x0h;
            __builtin_nontemporal_store(osc[0], reinterpret_cast<f32x4*>(out_score + qo));
            __builtin_nontemporal_store(osc[1], reinterpret_cast<f32x4*>(out_score + qo + 4));
            __builtin_nontemporal_store(oim[0], reinterpret_cast<f32x4*>(out_imp + qo));
            __builtin_nontemporal_store(oim[1], reinterpret_cast<f32x4*>(out_imp + qo + 4));
            __builtin_nontemporal_store(oun[0], reinterpret_cast<f32x4*>(out_unc + qo));
            __builtin_nontemporal_store(oun[1], reinterpret_cast<f32x4*>(out_unc + qo + 4));
        }
        __syncthreads();  // reads done before next pair's publish
    }
}

extern "C" void kernel_launch(void* const* d_in, const int* in_sizes, int n_in,
                              void* d_out, int out_size, void* d_ws, size_t ws_size,
                              hipStream_t stream) {
    const float* logit = (const float*)d_in[0];
    float* out = (float*)d_out;
    unsigned int* packed = (unsigned int*)d_ws;  // 8 MB

    k1_entropy_argmax<<<HW / 512, 256, 0, stream>>>(logit, packed);
    k23_box_score<<<256, NT, 0, stream>>>(packed, out, out + HW, out + 2 * HW);
}